// Round 13
// baseline (152.788 us; speedup 1.0000x reference)
//
#include <hip/hip_runtime.h>
#include <stdint.h>

#define NQ   8192
#define NB   2
#define KNN  10
#define K1   11                 // top-11 incl. self (dist 0 = global min key); dropped at end
#define NTOT (NB * NQ)
#define NGRP (NTOT / 64)        // 256 query groups
#define IDXMASK 0x1FFFu

// tau: per query, 11th-smallest key over a fixed 2048-point subsample (stride 4)
#define SUBS    2048
#define SSTRIDE 4
#define TW      16
#define CKI(s, c, lane) (((s) * TW + (c)) * 64 + (lane))

// scan: group of 64 queries x 4 blocks; each block scans 2048 candidates
#define HB    4
#define CPB   (NQ / HB)         // 2048
#define TILE  1024
#define WPB   8                 // waves per scan block (512 threads)
#define CPWT  (TILE / WPB)      // 128
#define CAPQ  40                // list capacity per (query, block); lambda ~12.3, ~7 sigma
#define LSTR  41

#define AGENT __HIP_MEMORY_SCOPE_AGENT

static __device__ __forceinline__ uint32_t umin32(uint32_t a, uint32_t b) { return a < b ? a : b; }
static __device__ __forceinline__ uint32_t umax32(uint32_t a, uint32_t b) { return a > b ? a : b; }
static __device__ __forceinline__ uint32_t aload(const uint32_t* p) {
    return __hip_atomic_load(p, __ATOMIC_RELAXED, AGENT);
}
static __device__ __forceinline__ void astore(uint32_t* p, uint32_t v) {
    __hip_atomic_store(p, v, __ATOMIC_RELAXED, AGENT);
}

static __device__ __forceinline__ void insert11(uint32_t (&l)[K1], uint32_t key) {
#pragma unroll
    for (int s = 0; s < K1; ++s) {
        const uint32_t m = l[s];
        l[s] = umin32(key, m);
        key  = umax32(key, m);
    }
}

// ---------------- kernel 1: per-query tau; zeroes the semaphores ----------------
__global__ __launch_bounds__(1024, 4) void plap_tau(
    const float* __restrict__ p1, uint32_t* __restrict__ tauG,
    uint32_t* __restrict__ sema, uint32_t* __restrict__ gsem)
{
    __shared__ float sx[SUBS], sy[SUBS], sz0[SUBS];    // 24 KB
    __shared__ uint32_t ck[K1 * TW * 64];              // 45056 B

    const int tid  = threadIdx.x;
    const int lane = tid & 63;
    const int wave = tid >> 6;
    const int wq   = __builtin_amdgcn_readfirstlane(wave);
    const int b    = blockIdx.x >> 7;
    const int qi   = ((blockIdx.x & 127) << 6) | lane;
    const float* __restrict__ P = p1 + (size_t)b * NQ * 3;

    if (tid == 0) sema[blockIdx.x] = 0u;               // runtime flush at kernel end
    if (blockIdx.x == 0 && tid == 1) gsem[0] = 0u;
#pragma unroll
    for (int t = tid; t < SUBS; t += 1024) {
        const float* src = P + (size_t)(t * SSTRIDE) * 3;
        sx[t] = src[0]; sy[t] = src[1]; sz0[t] = src[2];
    }
    const float qx = P[qi * 3 + 0];
    const float qy = P[qi * 3 + 1];
    const float qz = P[qi * 3 + 2];
    __syncthreads();

    uint32_t l[K1];
#pragma unroll
    for (int s = 0; s < K1; ++s) l[s] = 0xFFFFFFFFu;
    const int t0 = wq * (SUBS / TW);
#pragma unroll 4
    for (int t = t0; t < t0 + SUBS / TW; ++t) {
        const float dx = qx - sx[t], dy = qy - sy[t], dz = qz - sz0[t];
        const float d  = fmaf(dx, dx, fmaf(dy, dy, dz * dz));
        insert11(l, (__float_as_uint(d) & ~IDXMASK) | (uint32_t)(t * SSTRIDE));
    }
#pragma unroll
    for (int s = 0; s < K1; ++s) ck[CKI(s, wq, lane)] = l[s];
    __syncthreads();

    for (int st = 1; st < TW; st <<= 1) {              // tree-merge -> 11th of 2048
        if ((wq & (2 * st - 1)) == 0) {
            uint32_t A[K1];
#pragma unroll
            for (int s = 0; s < K1; ++s) A[s] = ck[CKI(s, wq, lane)];
#pragma unroll
            for (int e = 0; e < K1; ++e) insert11(A, ck[CKI(e, wq + st, lane)]);
            if (2 * st < TW) {
#pragma unroll
                for (int s = 0; s < K1; ++s) ck[CKI(s, wq, lane)] = A[s];
            } else {
                tauG[blockIdx.x * 64 + lane] = A[K1 - 1];
            }
        }
        __syncthreads();
    }
}

// ---------------- kernel 2: scan + last-arriver merge + last-group final sum ----------------
__global__ __launch_bounds__(512, 8) void plap_scan_merge(
    const float* __restrict__ p1, const float* __restrict__ p2,
    const uint32_t* __restrict__ tauG,
    uint32_t* __restrict__ keysG, uint32_t* __restrict__ cntG,
    uint32_t* __restrict__ sema, uint32_t* __restrict__ gsem,
    float* __restrict__ gout, float* __restrict__ out)
{
    __shared__ __align__(16) uint32_t shm[6848];
    float2*   sxy   = reinterpret_cast<float2*>(shm);          // [0,2048)  (x,y)
    float2*   szc   = reinterpret_cast<float2*>(shm + 2048);   // [2048,4096) (z,|c|^2)
    uint32_t* lists = shm + 4096;                              // [4096,6720)
    uint32_t* cnt   = shm + 6720;                              // [6720,6784)
    uint32_t* sflag = shm + 6784;
    uint32_t* sk    = shm;                                     // merge tree aliases tiles

    const int tid   = threadIdx.x;
    const int lane  = tid & 63;
    const int wave  = tid >> 6;
    const int wq    = __builtin_amdgcn_readfirstlane(wave);
    const int group = blockIdx.x >> 2;                 // 0..255
    const int hb    = blockIdx.x & 3;
    const int b     = group >> 7;
    const int qi    = ((group & 127) << 6) | lane;
    const int qidG  = group * 64 + lane;
    const float* __restrict__ P = p1 + (size_t)b * NQ * 3;

    const float qx = P[qi * 3 + 0];
    const float qy = P[qi * 3 + 1];
    const float qz = P[qi * 3 + 2];
    const uint32_t tq = tauG[qidG];
    const float q2   = fmaf(qx, qx, fmaf(qy, qy, qz * qz));
    const float tcmp = __uint_as_float(tq | IDXMASK) - q2 + 2e-3f;  // padded superset test

    if (tid < 64) cnt[tid] = 0;

    const int j0 = hb * CPB;
    for (int tile = 0; tile < CPB / TILE; ++tile) {
        const int jt = j0 + tile * TILE;
        __syncthreads();
#pragma unroll
        for (int c = tid; c < TILE; c += 512) {        // stage (x,y) and (z,|c|^2)
            const float* src = P + (size_t)(jt + c) * 3;
            const float x = src[0], y = src[1], z = src[2];
            sxy[c] = make_float2(x, y);
            szc[c] = make_float2(z, fmaf(x, x, fmaf(y, y, z * z)));
        }
        __syncthreads();

        const int c0 = wq * CPWT;
#pragma unroll 8
        for (int t = 0; t < CPWT; ++t) {
            const int c = c0 + t;
            const float2 a  = sxy[c];                  // ds_read_b64 broadcast
            const float2 zc = szc[c];                  // ds_read_b64 broadcast
            const float s3  = fmaf(qx, a.x, fmaf(qy, a.y, qz * zc.x));
            const float dpr = fmaf(-2.0f, s3, zc.y);   // |c|^2 - 2 q.c = d - |q|^2
            if (dpr <= tcmp) {
                const float dx = qx - a.x, dy = qy - a.y, dz = qz - zc.x;
                const float d  = fmaf(dx, dx, fmaf(dy, dy, dz * dz));  // exact key formula
                const uint32_t key = (__float_as_uint(d) & ~IDXMASK) | (uint32_t)(jt + c);
                const uint32_t old = atomicAdd(&cnt[lane], 1u);
                if (old < CAPQ) lists[lane * LSTR + old] = key;
            }
        }
    }
    __syncthreads();

    // write-out via agent-scope (LLC-coherent) stores
    if (tid < 64) astore(&cntG[(size_t)qidG * HB + hb], cnt[tid]);
    const uint32_t mycnt = umin32(cnt[lane], CAPQ);
    uint32_t* __restrict__ dst = keysG + (size_t)qidG * (HB * CAPQ) + (size_t)hb * CAPQ;
    for (int s = wq; s < (int)mycnt; s += WPB)
        astore(&dst[s], lists[lane * LSTR + s]);

    __syncthreads();                                   // s_waitcnt vmcnt(0): all stores at LLC
    if (tid == 0) {
        const uint32_t old = __hip_atomic_fetch_add(&sema[group], 1u,
                                 __ATOMIC_RELAXED, AGENT);
        sflag[0] = (old == HB - 1) ? 1u : 0u;
    }
    __syncthreads();
    if (!sflag[0]) return;

    // ---------------- merge (last-arriving block of this group) ----------------
    uint32_t F[K1];
#pragma unroll
    for (int s = 0; s < K1; ++s) F[s] = 0xFFFFFFFFu;

    if (wq < HB) {
        const uint32_t c = aload(&cntG[(size_t)qidG * HB + wq]);
        if (c <= CAPQ) {
            const uint32_t* __restrict__ src =
                keysG + (size_t)qidG * (HB * CAPQ) + (size_t)wq * CAPQ;
            uint32_t s = 0;
            for (; s + 4 <= c; s += 4) {
                const uint32_t k0 = aload(src + s + 0);
                const uint32_t k1 = aload(src + s + 1);
                const uint32_t k2 = aload(src + s + 2);
                const uint32_t k3 = aload(src + s + 3);
                insert11(F, k0); insert11(F, k1); insert11(F, k2); insert11(F, k3);
            }
            for (; s < c; ++s) insert11(F, aload(src + s));
        } else {
            // exact fallback (P ~ 1e-9): rescan this quarter
            for (int j = wq * CPB; j < (wq + 1) * CPB; ++j) {
                const float dx = qx - P[j * 3 + 0];
                const float dy = qy - P[j * 3 + 1];
                const float dz = qz - P[j * 3 + 2];
                const float d  = fmaf(dx, dx, fmaf(dy, dy, dz * dz));
                insert11(F, (__float_as_uint(d) & ~IDXMASK) | (uint32_t)j);
            }
        }
#pragma unroll
        for (int s = 0; s < K1; ++s) sk[(wq * K1 + s) * 64 + lane] = F[s];
    }
    for (int st = 1; st < HB; st <<= 1) {
        __syncthreads();
        if (wq < HB && (wq & (2 * st - 1)) == 0) {
#pragma unroll
            for (int e = 0; e < K1; ++e) insert11(F, sk[((wq + st) * K1 + e) * 64 + lane]);
            if (2 * st < HB) {
#pragma unroll
                for (int s = 0; s < K1; ++s) sk[(wq * K1 + s) * 64 + lane] = F[s];
            }
        }
    }

    if (wq == 0) {
        const float* __restrict__ P2 = p2 + (size_t)b * NQ * 3;
        float s1x = 0.f, s1y = 0.f, s1z = 0.f, s2x = 0.f, s2y = 0.f, s2z = 0.f;
#pragma unroll
        for (int s = 1; s < K1; ++s) {                 // F[0] = self (d = 0)
            const int n = (int)(F[s] & IDXMASK);
            s1x += P[n * 3 + 0];  s1y += P[n * 3 + 1];  s1z += P[n * 3 + 2];
            s2x += P2[n * 3 + 0]; s2y += P2[n * 3 + 1]; s2z += P2[n * 3 + 2];
        }
        const float invk = 1.0f / (float)KNN;
        const float lx = (s1x * invk - qx) - (s2x * invk - P2[qi * 3 + 0]);
        const float ly = (s1y * invk - qy) - (s2y * invk - P2[qi * 3 + 1]);
        const float lz = (s1z * invk - qz) - (s2z * invk - P2[qi * 3 + 2]);
        float acc = fabsf(lx) + fabsf(ly) + fabsf(lz);
#pragma unroll
        for (int off = 32; off > 0; off >>= 1)
            acc += __shfl_down(acc, off, 64);

        // group partial -> gout, then last group sums and writes out
        uint32_t g_old = 0;
        if (lane == 0) {
            __hip_atomic_store(&gout[group], acc, __ATOMIC_RELAXED, AGENT);
            g_old = __hip_atomic_fetch_add(gsem, 1u, __ATOMIC_RELEASE, AGENT);
        }
        g_old = (uint32_t)__shfl((int)g_old, 0, 64);
        if (g_old == NGRP - 1) {
            float tot = 0.f;
#pragma unroll
            for (int k = 0; k < NGRP / 64; ++k) {
                float v = __uint_as_float(aload((const uint32_t*)&gout[k * 64 + lane]));
                tot += v;
            }
#pragma unroll
            for (int off = 32; off > 0; off >>= 1)
                tot += __shfl_down(tot, off, 64);
            if (lane == 0)
                __hip_atomic_store((uint32_t*)out,
                    __float_as_uint(tot * (1.0f / (float)(NTOT * 3))),
                    __ATOMIC_RELAXED, AGENT);
        }
    }
}

extern "C" void kernel_launch(void* const* d_in, const int* in_sizes, int n_in,
                              void* d_out, int out_size, void* d_ws, size_t ws_size,
                              hipStream_t stream) {
    const float* p1 = (const float*)d_in[0];
    const float* p2 = (const float*)d_in[1];
    float* out      = (float*)d_out;

    // ws: tau 64KB | cnt 256KB | sema 1KB | gsem 4B | gout 1KB | keys 10.5MB
    uint32_t* tauG  = (uint32_t*)d_ws;
    uint32_t* cntG  = tauG + NTOT;
    uint32_t* sema  = cntG + (size_t)NTOT * HB;
    uint32_t* gsem  = sema + NGRP;
    float*    gout  = (float*)(gsem + 1);
    uint32_t* keysG = (uint32_t*)(gout + NGRP);

    plap_tau<<<dim3(NGRP), dim3(TW * 64), 0, stream>>>(p1, tauG, sema, gsem);
    plap_scan_merge<<<dim3(NGRP * HB), dim3(WPB * 64), 0, stream>>>(
        p1, p2, tauG, keysG, cntG, sema, gsem, gout, out);
}

// Round 14
// 135.399 us; speedup vs baseline: 1.1284x; 1.1284x over previous
//
#include <hip/hip_runtime.h>
#include <stdint.h>

#define NQ   8192
#define NB   2
#define KNN  10
#define K1   11                 // top-11 incl. self (dist 0 = global min key); dropped at end
#define NTOT (NB * NQ)
#define IDXMASK 0x1FFFu
#define PAD  2e-3f              // dpr-vs-exact-key slack (fp err <= ~4e-4)

// tau: per query, 11th-smallest dpr over a fixed 2048-point subsample (stride 4)
#define SUBS    2048
#define SSTRIDE 4
#define TW      16              // waves per tau block (1024 thr, 64 queries)
#define CKI(s, c, lane) (((s) * TW + (c)) * 64 + (lane))

// scan: group of 128 queries x 8 blocks; each block scans 1024 candidates
#define HB    8
#define CPB   (NQ / HB)         // 1024
#define WPB   8                 // waves per scan block (512 threads)
#define CPWT  (CPB / WPB)       // 128 broadcasts per wave (x2 queries)
#define CAPQ  24                // per (query, block); lambda ~5.5, ~8 sigma
#define LSTR  25

static __device__ __forceinline__ uint32_t umin32(uint32_t a, uint32_t b) { return a < b ? a : b; }
static __device__ __forceinline__ uint32_t umax32(uint32_t a, uint32_t b) { return a > b ? a : b; }

static __device__ __forceinline__ void insert11(uint32_t (&l)[K1], uint32_t key) {
#pragma unroll
    for (int s = 0; s < K1; ++s) {
        const uint32_t m = l[s];
        l[s] = umin32(key, m);
        key  = umax32(key, m);
    }
}
static __device__ __forceinline__ void insert11f(float (&l)[K1], float v) {
#pragma unroll
    for (int s = 0; s < K1; ++s) {
        const float m = l[s];
        l[s] = fminf(v, m);
        v    = fmaxf(v, m);
    }
}

// ---------------- kernel 1: per-query tau (dpr space); zeroes loss accumulator ----------------
__global__ __launch_bounds__(1024, 4) void plap_tau(
    const float* __restrict__ p1, float* __restrict__ tauDpr, float* __restrict__ out)
{
    __shared__ float2 sxy[SUBS];                       // 16 KB (x,y)
    __shared__ float2 szc[SUBS];                       // 16 KB (z,|c|^2)
    __shared__ float  ck[K1 * TW * 64];                // 45056 B

    const int tid  = threadIdx.x;
    const int lane = tid & 63;
    const int wave = tid >> 6;
    const int wq   = __builtin_amdgcn_readfirstlane(wave);
    const int b    = blockIdx.x >> 7;
    const int qi   = ((blockIdx.x & 127) << 6) | lane;
    const float* __restrict__ P = p1 + (size_t)b * NQ * 3;

    if (blockIdx.x == 0 && tid == 0) out[0] = 0.0f;    // replaces memset dispatch
#pragma unroll
    for (int t = tid; t < SUBS; t += 1024) {
        const float* src = P + (size_t)(t * SSTRIDE) * 3;
        const float x = src[0], y = src[1], z = src[2];
        sxy[t] = make_float2(x, y);
        szc[t] = make_float2(z, fmaf(x, x, fmaf(y, y, z * z)));
    }
    const float qx = P[qi * 3 + 0];
    const float qy = P[qi * 3 + 1];
    const float qz = P[qi * 3 + 2];
    __syncthreads();

    float l[K1];
#pragma unroll
    for (int s = 0; s < K1; ++s) l[s] = __builtin_inff();
    const int t0 = wq * (SUBS / TW);                   // 128 samples per wave
#pragma unroll 4
    for (int t = t0; t < t0 + SUBS / TW; ++t) {
        const float2 a  = sxy[t];
        const float2 zc = szc[t];
        const float s3  = fmaf(qx, a.x, fmaf(qy, a.y, qz * zc.x));
        insert11f(l, fmaf(-2.0f, s3, zc.y));           // dpr = |c|^2 - 2 q.c
    }
#pragma unroll
    for (int s = 0; s < K1; ++s) ck[CKI(s, wq, lane)] = l[s];
    __syncthreads();

    for (int st = 1; st < TW; st <<= 1) {              // tree-merge -> 11th of 2048
        if ((wq & (2 * st - 1)) == 0) {
            float A[K1];
#pragma unroll
            for (int s = 0; s < K1; ++s) A[s] = ck[CKI(s, wq, lane)];
#pragma unroll
            for (int e = 0; e < K1; ++e) insert11f(A, ck[CKI(e, wq + st, lane)]);
            if (2 * st < TW) {
#pragma unroll
                for (int s = 0; s < K1; ++s) ck[CKI(s, wq, lane)] = A[s];
            } else {
                tauDpr[blockIdx.x * 64 + lane] = A[K1 - 1];
            }
        }
        __syncthreads();
    }
}

// ---------------- kernel 2: filtered scan, 2 queries/lane, dot-form filter ----------------
__global__ __launch_bounds__(512, 8) void plap_scan(
    const float* __restrict__ p1, const float* __restrict__ tauDpr,
    uint32_t* __restrict__ keysG, uint32_t* __restrict__ cntG)
{
    __shared__ float2 sxy[CPB];                        // 8 KB
    __shared__ float2 szc[CPB];                        // 8 KB
    __shared__ uint32_t lists[128 * LSTR];             // 12800 B
    __shared__ uint32_t cnt[128];                      // -> ~29.3 KB (4 blocks/CU)

    const int tid   = threadIdx.x;
    const int lane  = tid & 63;
    const int wave  = tid >> 6;
    const int wq    = __builtin_amdgcn_readfirstlane(wave);
    const int group = blockIdx.x >> 3;                 // 0..127 (128-query groups)
    const int hb    = blockIdx.x & 7;
    const int b     = group >> 6;                      // 64 groups per batch
    const int qi0   = ((group & 63) << 7) | lane;      // query index in batch
    const int qi1   = qi0 + 64;
    const int qid0  = (group << 7) | lane;             // global query id
    const int qid1  = qid0 + 64;
    const float* __restrict__ P = p1 + (size_t)b * NQ * 3;

    const float q0x = P[qi0 * 3 + 0], q0y = P[qi0 * 3 + 1], q0z = P[qi0 * 3 + 2];
    const float q1x = P[qi1 * 3 + 0], q1y = P[qi1 * 3 + 1], q1z = P[qi1 * 3 + 2];
    const float tc0 = tauDpr[qid0] + PAD;
    const float tc1 = tauDpr[qid1] + PAD;

    if (tid < 128) cnt[tid] = 0;
    const int j0 = hb * CPB;
#pragma unroll
    for (int c = tid; c < CPB; c += 512) {             // stage 1024 candidates
        const float* src = P + (size_t)(j0 + c) * 3;
        const float x = src[0], y = src[1], z = src[2];
        sxy[c] = make_float2(x, y);
        szc[c] = make_float2(z, fmaf(x, x, fmaf(y, y, z * z)));
    }
    __syncthreads();

    const int c0 = wq * CPWT;
#pragma unroll 8
    for (int t = 0; t < CPWT; ++t) {
        const int c = c0 + t;
        const float2 a  = sxy[c];                      // ds_read_b64 broadcast
        const float2 zc = szc[c];                      // ds_read_b64 broadcast
        const float s30 = fmaf(q0x, a.x, fmaf(q0y, a.y, q0z * zc.x));
        const float s31 = fmaf(q1x, a.x, fmaf(q1y, a.y, q1z * zc.x));
        const float dp0 = fmaf(-2.0f, s30, zc.y);
        const float dp1 = fmaf(-2.0f, s31, zc.y);
        if (dp0 <= tc0) {
            const float dx = q0x - a.x, dy = q0y - a.y, dz = q0z - zc.x;
            const float d  = fmaf(dx, dx, fmaf(dy, dy, dz * dz));   // exact key formula
            const uint32_t key = (__float_as_uint(d) & ~IDXMASK) | (uint32_t)(j0 + c);
            const uint32_t old = atomicAdd(&cnt[lane], 1u);
            if (old < CAPQ) lists[lane * LSTR + old] = key;
        }
        if (dp1 <= tc1) {
            const float dx = q1x - a.x, dy = q1y - a.y, dz = q1z - zc.x;
            const float d  = fmaf(dx, dx, fmaf(dy, dy, dz * dz));
            const uint32_t key = (__float_as_uint(d) & ~IDXMASK) | (uint32_t)(j0 + c);
            const uint32_t old = atomicAdd(&cnt[lane + 64], 1u);
            if (old < CAPQ) lists[(lane + 64) * LSTR + old] = key;
        }
    }
    __syncthreads();

    // write-out: counts + keys, query-contiguous layout [qid][hb][slot]
    if (tid < 128) cntG[(size_t)((group << 7) | tid) * HB + hb] = cnt[tid];
    {
        const uint32_t c0n = umin32(cnt[lane], CAPQ);
        uint32_t* __restrict__ dst = keysG + (size_t)qid0 * (HB * CAPQ) + (size_t)hb * CAPQ;
        for (int s = wq; s < (int)c0n; s += WPB) dst[s] = lists[lane * LSTR + s];
        const uint32_t c1n = umin32(cnt[lane + 64], CAPQ);
        uint32_t* __restrict__ dst1 = keysG + (size_t)qid1 * (HB * CAPQ) + (size_t)hb * CAPQ;
        for (int s = wq; s < (int)c1n; s += WPB) dst1[s] = lists[(lane + 64) * LSTR + s];
    }
}

// ---------------- kernel 3: parallel merge (4 waves x 2 lists) + loss ----------------
__global__ __launch_bounds__(256) void plap_merge_loss(
    const float* __restrict__ p1, const float* __restrict__ p2,
    const uint32_t* __restrict__ keysG, const uint32_t* __restrict__ cntG,
    float* __restrict__ out)
{
    __shared__ uint32_t sk[4 * K1 * 64];               // 11264 B, lane-major
    const int ql = threadIdx.x & 63;
    const int w  = threadIdx.x >> 6;                   // 0..3
    const int wu = __builtin_amdgcn_readfirstlane(w);
    const int qid = blockIdx.x * 64 + ql;              // 0..NTOT-1
    const int b   = qid >> 13;
    const int qi  = qid & (NQ - 1);
    const float* __restrict__ P1 = p1 + (size_t)b * NQ * 3;
    const float* __restrict__ P2 = p2 + (size_t)b * NQ * 3;

    const float qx = P1[qi * 3 + 0];
    const float qy = P1[qi * 3 + 1];
    const float qz = P1[qi * 3 + 2];

    uint32_t F[K1];
#pragma unroll
    for (int s = 0; s < K1; ++s) F[s] = 0xFFFFFFFFu;

#pragma unroll
    for (int hh = 0; hh < 2; ++hh) {
        const int h = 2 * wu + hh;
        const uint32_t c = cntG[(size_t)qid * HB + h];
        if (c <= CAPQ) {
            const uint32_t* __restrict__ src =
                keysG + (size_t)qid * (HB * CAPQ) + (size_t)h * CAPQ;
            for (uint32_t s = 0; s < c; ++s) insert11(F, src[s]);
        } else {
            // exact fallback (P ~ 1e-9): rescan this eighth
            for (int j = h * CPB; j < (h + 1) * CPB; ++j) {
                const float dx = qx - P1[j * 3 + 0];
                const float dy = qy - P1[j * 3 + 1];
                const float dz = qz - P1[j * 3 + 2];
                const float d  = fmaf(dx, dx, fmaf(dy, dy, dz * dz));
                insert11(F, (__float_as_uint(d) & ~IDXMASK) | (uint32_t)j);
            }
        }
    }

#pragma unroll
    for (int s = 0; s < K1; ++s) sk[(wu * K1 + s) * 64 + ql] = F[s];
    for (int st = 1; st < 4; st <<= 1) {
        __syncthreads();
        if ((wu & (2 * st - 1)) == 0) {
#pragma unroll
            for (int e = 0; e < K1; ++e) insert11(F, sk[((wu + st) * K1 + e) * 64 + ql]);
            if (2 * st < 4) {
#pragma unroll
                for (int s = 0; s < K1; ++s) sk[(wu * K1 + s) * 64 + ql] = F[s];
            }
        }
    }

    if (wu == 0) {
        float s1x = 0.f, s1y = 0.f, s1z = 0.f, s2x = 0.f, s2y = 0.f, s2z = 0.f;
#pragma unroll
        for (int s = 1; s < K1; ++s) {                 // F[0] = self (d = 0)
            const int n = (int)(F[s] & IDXMASK);
            s1x += P1[n * 3 + 0]; s1y += P1[n * 3 + 1]; s1z += P1[n * 3 + 2];
            s2x += P2[n * 3 + 0]; s2y += P2[n * 3 + 1]; s2z += P2[n * 3 + 2];
        }
        const float invk = 1.0f / (float)KNN;
        const float lx = (s1x * invk - qx) - (s2x * invk - P2[qi * 3 + 0]);
        const float ly = (s1y * invk - qy) - (s2y * invk - P2[qi * 3 + 1]);
        const float lz = (s1z * invk - qz) - (s2z * invk - P2[qi * 3 + 2]);
        float acc = fabsf(lx) + fabsf(ly) + fabsf(lz);
#pragma unroll
        for (int off = 32; off > 0; off >>= 1)
            acc += __shfl_down(acc, off, 64);
        if (ql == 0) atomicAdd(out, acc * (1.0f / (float)(NTOT * 3)));
    }
}

extern "C" void kernel_launch(void* const* d_in, const int* in_sizes, int n_in,
                              void* d_out, int out_size, void* d_ws, size_t ws_size,
                              hipStream_t stream) {
    const float* p1 = (const float*)d_in[0];
    const float* p2 = (const float*)d_in[1];
    float* out      = (float*)d_out;

    // ws: tauDpr 64 KB | cnt 512 KB | keys (NTOT*HB*CAPQ*4 = 12.6 MB)
    float*    tauD  = (float*)d_ws;
    uint32_t* cntG  = (uint32_t*)(tauD + NTOT);
    uint32_t* keysG = cntG + (size_t)NTOT * HB;

    plap_tau <<<dim3(NTOT / 64), dim3(TW * 64), 0, stream>>>(p1, tauD, out);
    plap_scan<<<dim3(NTOT / 128 * HB), dim3(WPB * 64), 0, stream>>>(p1, tauD, keysG, cntG);
    plap_merge_loss<<<dim3(NTOT / 64), dim3(256), 0, stream>>>(p1, p2, keysG, cntG, out);
}